// Round 4
// baseline (327.172 us; speedup 1.0000x reference)
//
#include <hip/hip_runtime.h>
#include <hip/hip_bf16.h>

#define HH 512
#define WW 512
#define HWSZ (HH*WW)
#define NB 32
#define NLD 100000
#define NF 16
#define EPSV 1e-3f
#define TILE 16
#define GR (TILE+4)    // grid halo tile 20x20
#define YR (TILE+2)    // y1/proj tile 18x18
#define YRYR (YR*YR)   // 324
#define NGRP 21        // ceil(324/16) pixel-groups for MFMA
#define PSLOTS (NGRP*16)
#define PSTR 10

#define RGB 14              // log2 cells per scatter region
#define RCELLS (1<<RGB)     // 16384 cells = 64KB LDS
#define NREG (HWSZ/RCELLS)  // 16 regions per batch

typedef __attribute__((ext_vector_type(8))) short bf16x8;
typedef __attribute__((ext_vector_type(4))) float f32x4;

static __device__ __forceinline__ short f2bf(float f) {
  __hip_bfloat16 h = __float2bfloat16(f);
  return __builtin_bit_cast(short, h);
}

// ---- scatter via LDS-privatized regions: zero global atomics, absorbs the
// grid zeroing (every cell of the region is written: sum or 0). Block
// (b = j&31, r = j>>5) -> XCD b%8, so idx (400KB) and x[b] (400KB) are
// L2-resident per XCD across that batch's 16 region-blocks. ----
__global__ __launch_bounds__(256) void scatter_k(const float* __restrict__ x,
    const int* __restrict__ idx, float* __restrict__ grid) {
  __shared__ float s_acc[RCELLS];
  const int lid = threadIdx.x;
  const int j = blockIdx.x;
  const int b = j & 31;
  const int r = j >> 5;

  for (int q = lid; q < RCELLS; q += 256) s_acc[q] = 0.f;
  __syncthreads();

  const float* xb = x + (size_t)b*NLD;
  #pragma unroll 4
  for (int i0 = 0; i0 < NLD; i0 += 256) {
    int i = i0 + lid;
    if (i < NLD) {
      int cell = idx[i];
      if ((cell >> RGB) == r)
        atomicAdd(&s_acc[cell & (RCELLS-1)], xb[i]);   // ds_add_f32
    }
  }
  __syncthreads();

  float* gout = grid + (size_t)b*HWSZ + ((size_t)r << RGB);
  for (int q = lid; q < RCELLS/4; q += 256)
    *(float4*)(gout + q*4) = *(const float4*)(s_acc + q*4);
}

__global__ __launch_bounds__(256) void gather_k(const float* __restrict__ x,
    const int* __restrict__ idx, const float* __restrict__ y, float* __restrict__ out) {
  int j = blockIdx.x;
  int b = j & 31, chunk = j >> 5;
  int i = chunk*256 + threadIdx.x;
  if (i >= NLD) return;
  out[(size_t)b*NLD + i] = x[(size_t)b*NLD + i] + y[(size_t)b*HWSZ + idx[i]];
}

__global__ __launch_bounds__(256) void conv_k(const float* __restrict__ grid,
    const float* __restrict__ w1g, const float* __restrict__ b1g,
    const float* __restrict__ gammag, const float* __restrict__ betag,
    const float* __restrict__ mmg, const float* __restrict__ mvg,
    const float* __restrict__ w2g, const float* __restrict__ b2g,
    float* __restrict__ y)
{
  __shared__ float s_grid[GR][GR];
  __shared__ __align__(16) short s_y1b[PSLOTS][NF];   // y1 post-BN, bf16
  __shared__ float s_proj[PSLOTS][PSTR];
  __shared__ float s_w1[9][NF];
  __shared__ float s_b1[NF], s_bnA[NF], s_bnB[NF];

  const int lid = threadIdx.x;
  const int j = blockIdx.x;
  const int b = j & 31;                    // XCD-affine batch
  const int tile = j >> 5;
  const int ty0 = (tile >> 5) * TILE, tx0 = (tile & 31) * TILE;
  const float* gb = grid + (size_t)b*HWSZ;

  // A-fragment for proj MFMA: A[m=tap][k=ch]; lane l: m=l&15, k=(l>>4)*8+jj
  const int l = lid & 63;
  bf16x8 afrag;
  #pragma unroll
  for (int jj = 0; jj < 8; ++jj) {
    int m = l & 15, c = (l >> 4)*8 + jj;
    float wv = (m < 9 && c < NF) ? w2g[m*NF + c] : 0.f;
    afrag[jj] = f2bf(wv);
  }

  if (lid < 144) s_w1[lid/NF][lid%NF] = w1g[lid];
  if (lid >= 192 && lid < 192+NF) {
    int c = lid - 192;
    float sc = gammag[c] * rsqrtf(mvg[c] + EPSV);
    s_bnA[c] = sc;
    s_bnB[c] = betag[c] - mmg[c]*sc;
    s_b1[c] = b1g[c];
  }

  for (int q = lid; q < GR*GR; q += 256) {
    int r = q / GR, c = q - r*GR;
    int gh = ty0 - 2 + r, gw = tx0 - 2 + c;
    float v = 0.f;
    if ((unsigned)gh < HH && (unsigned)gw < WW) v = gb[gh*WW + gw];
    s_grid[r][c] = v;
  }
  __syncthreads();

  // ---- phase A: conv1+relu+BN (fp32, quad-split channels) -> s_y1b bf16 ----
  {
    const int g = lid >> 2, k = lid & 3, c0 = k*4;
    float rw1[9][4], ra[4], rb[4], rbias[4];
    #pragma unroll
    for (int t = 0; t < 9; ++t)
      #pragma unroll
      for (int jj = 0; jj < 4; ++jj) rw1[t][jj] = s_w1[t][c0+jj];
    #pragma unroll
    for (int jj = 0; jj < 4; ++jj) { ra[jj]=s_bnA[c0+jj]; rb[jj]=s_bnB[c0+jj]; rbias[jj]=s_b1[c0+jj]; }

    for (int p = g; p < YRYR; p += 64) {
      int r = p / YR, c = p - r*YR;
      int yh = ty0 - 1 + r, yw = tx0 - 1 + c;
      float vmask = ((unsigned)yh < HH && (unsigned)yw < WW) ? 1.f : 0.f;
      float gg[9];
      #pragma unroll
      for (int dy = 0; dy < 3; ++dy)
        #pragma unroll
        for (int dx = 0; dx < 3; ++dx) gg[dy*3+dx] = s_grid[r+dy][c+dx];
      short4 hv;
      short* hp = (short*)&hv;
      #pragma unroll
      for (int jj = 0; jj < 4; ++jj) {
        float a = rbias[jj];
        #pragma unroll
        for (int t = 0; t < 9; ++t) a = fmaf(gg[t], rw1[t][jj], a);
        a = fmaxf(a, 0.f);
        hp[jj] = f2bf(vmask * fmaf(a, ra[jj], rb[jj]));  // OOB y1 -> 0
      }
      *(short4*)&s_y1b[p][c0] = hv;
    }
  }
  __syncthreads();

  // ---- phase P: proj[t][p] = sum_c w2[t][c]*y1[p][c] via one MFMA / 16 px ----
  {
    const int wid = lid >> 6;
    for (int grp = wid; grp < NGRP; grp += 4) {
      int p = grp*16 + (l & 15);
      bf16x8 bfrag = {0,0,0,0,0,0,0,0};     // B[k=ch][n=px]: k=(l>>4)*8+jj
      if (l < 32) bfrag = *(const bf16x8*)&s_y1b[p][(l >> 4)*8];
      f32x4 d = {0.f,0.f,0.f,0.f};
      d = __builtin_amdgcn_mfma_f32_16x16x32_bf16(afrag, bfrag, d, 0, 0, 0);
      #pragma unroll
      for (int r4 = 0; r4 < 4; ++r4) {
        int t = (l >> 4)*4 + r4;            // C: col=lane&15, row=(lane>>4)*4+reg
        if (t < 9) s_proj[p][t] = d[r4];
      }
    }
  }
  __syncthreads();

  // ---- phase B: out = b2 + sum_t proj[t] at shifted pixel ----
  {
    const int ty = lid >> 4, tx = lid & 15;
    float acc = b2g[0];
    #pragma unroll
    for (int kh = 0; kh < 3; ++kh)
      #pragma unroll
      for (int kw = 0; kw < 3; ++kw)
        acc += s_proj[(ty+kh)*YR + (tx+kw)][kh*3+kw];
    y[(size_t)b*HWSZ + (size_t)(ty0+ty)*WW + (tx0+tx)] = acc;
  }
}

extern "C" void kernel_launch(void* const* d_in, const int* in_sizes, int n_in,
                              void* d_out, int out_size, void* d_ws, size_t ws_size,
                              hipStream_t stream) {
  const float* x     = (const float*)d_in[0];
  const float* w1    = (const float*)d_in[1];
  const float* b1    = (const float*)d_in[2];
  const float* gamma = (const float*)d_in[3];
  const float* beta  = (const float*)d_in[4];
  const float* mmean = (const float*)d_in[5];
  const float* mvar  = (const float*)d_in[6];
  const float* w2    = (const float*)d_in[7];
  const float* b2    = (const float*)d_in[8];
  const int*   idx   = (const int*)d_in[9];
  float* out = (float*)d_out;

  float* grid = (float*)d_ws;
  float* yout = grid + (size_t)NB*HWSZ;

  // scatter writes every grid cell (sum or zero) -> no memset needed
  scatter_k<<<dim3(NB*NREG), dim3(256), 0, stream>>>(x, idx, grid);

  conv_k<<<dim3(32 * (HH/TILE) * (WW/TILE)), dim3(256), 0, stream>>>(
      grid, w1, b1, gamma, beta, mmean, mvar, w2, b2, yout);

  int gblocks = 32 * ((NLD + 255) / 256);
  gather_k<<<dim3(gblocks), dim3(256), 0, stream>>>(x, idx, yout, out);
}

// Round 5
// 184.404 us; speedup vs baseline: 1.7742x; 1.7742x over previous
//
#include <hip/hip_runtime.h>
#include <hip/hip_bf16.h>

#define HH 512
#define WW 512
#define HWSZ (HH*WW)
#define NB 32
#define NLD 100000
#define NF 16
#define EPSV 1e-3f
#define TILE 16
#define GR (TILE+4)    // grid halo tile 20x20
#define YR (TILE+2)    // y1/proj tile 18x18
#define YRYR (YR*YR)   // 324
#define NGRP 21        // ceil(324/16) pixel-groups for MFMA
#define PSLOTS (NGRP*16)
#define PSTR 10

#define RGB 14              // log2 cells per scatter region
#define RCELLS (1<<RGB)     // 16384 cells = 64KB LDS
#define NREG (HWSZ/RCELLS)  // 16 regions per batch
#define CAP 8192            // bucket capacity (expect 6250 +- 77, 25 sigma headroom)

typedef __attribute__((ext_vector_type(8))) short bf16x8;
typedef __attribute__((ext_vector_type(4))) float f32x4;

static __device__ __forceinline__ short f2bf(float f) {
  __hip_bfloat16 h = __float2bfloat16(f);
  return __builtin_bit_cast(short, h);
}

// ---- pass 0: bin the (batch-independent) indices into 16 region buckets.
// entry = (i << 14) | (cell & 16383), 31 bits. One LDS histogram + 16 global
// atomics per block reserve contiguous slots; order within bucket is
// nondeterministic but summation later is order-insensitive within fp tol. ----
__global__ __launch_bounds__(256) void bin_k(const int* __restrict__ idx,
    unsigned* __restrict__ g_cnt, unsigned* __restrict__ g_bucket) {
  __shared__ unsigned hist[NREG], base[NREG];
  const int lid = threadIdx.x;
  if (lid < NREG) hist[lid] = 0;
  __syncthreads();
  int i = blockIdx.x*256 + lid;
  int r = -1; unsigned rank = 0, entry = 0;
  if (i < NLD) {
    int cell = idx[i];
    r = cell >> RGB;
    entry = ((unsigned)i << RGB) | (unsigned)(cell & (RCELLS-1));
    rank = atomicAdd(&hist[r], 1u);
  }
  __syncthreads();
  if (lid < NREG) base[lid] = atomicAdd(&g_cnt[lid], hist[lid]);
  __syncthreads();
  if (r >= 0) {
    unsigned pos = base[r] + rank;
    if (pos < CAP) g_bucket[(size_t)r*CAP + pos] = entry;
  }
}

// ---- pass 1: block (b = j&31 -> XCD b%8, r = j>>5) accumulates its region
// in LDS from the ~6250 bucket entries, then streams the 64KB region out
// (every cell written: sum or zero -> absorbs grid zeroing). ----
__global__ __launch_bounds__(256) void scatter_k(const float* __restrict__ x,
    const unsigned* __restrict__ g_cnt, const unsigned* __restrict__ g_bucket,
    float* __restrict__ grid) {
  __shared__ float s_acc[RCELLS];
  const int lid = threadIdx.x;
  const int j = blockIdx.x;
  const int b = j & 31;
  const int r = j >> 5;

  float4 z = make_float4(0.f, 0.f, 0.f, 0.f);
  for (int q = lid; q < RCELLS/4; q += 256) ((float4*)s_acc)[q] = z;
  __syncthreads();

  const unsigned n = min(g_cnt[r], (unsigned)CAP);
  const float* xb = x + (size_t)b*NLD;
  const unsigned* bk = g_bucket + (size_t)r*CAP;
  #pragma unroll 4
  for (unsigned k = lid; k < n; k += 256) {
    unsigned e = bk[k];
    atomicAdd(&s_acc[e & (RCELLS-1)], xb[e >> RGB]);   // ds_add_f32
  }
  __syncthreads();

  float* gout = grid + (size_t)b*HWSZ + ((size_t)r << RGB);
  for (int q = lid; q < RCELLS/4; q += 256)
    ((float4*)gout)[q] = ((const float4*)s_acc)[q];
}

__global__ __launch_bounds__(256) void gather_k(const float* __restrict__ x,
    const int* __restrict__ idx, const float* __restrict__ y, float* __restrict__ out) {
  int j = blockIdx.x;
  int b = j & 31, chunk = j >> 5;
  int i = chunk*256 + threadIdx.x;
  if (i >= NLD) return;
  out[(size_t)b*NLD + i] = x[(size_t)b*NLD + i] + y[(size_t)b*HWSZ + idx[i]];
}

__global__ __launch_bounds__(256) void conv_k(const float* __restrict__ grid,
    const float* __restrict__ w1g, const float* __restrict__ b1g,
    const float* __restrict__ gammag, const float* __restrict__ betag,
    const float* __restrict__ mmg, const float* __restrict__ mvg,
    const float* __restrict__ w2g, const float* __restrict__ b2g,
    float* __restrict__ y)
{
  __shared__ float s_grid[GR][GR];
  __shared__ __align__(16) short s_y1b[PSLOTS][NF];   // y1 post-BN, bf16
  __shared__ float s_proj[PSLOTS][PSTR];
  __shared__ float s_w1[9][NF];
  __shared__ float s_b1[NF], s_bnA[NF], s_bnB[NF];

  const int lid = threadIdx.x;
  const int j = blockIdx.x;
  const int b = j & 31;                    // XCD-affine batch
  const int tile = j >> 5;
  const int ty0 = (tile >> 5) * TILE, tx0 = (tile & 31) * TILE;
  const float* gb = grid + (size_t)b*HWSZ;

  // A-fragment for proj MFMA: A[m=tap][k=ch]; lane l: m=l&15, k=(l>>4)*8+jj
  const int l = lid & 63;
  bf16x8 afrag;
  #pragma unroll
  for (int jj = 0; jj < 8; ++jj) {
    int m = l & 15, c = (l >> 4)*8 + jj;
    float wv = (m < 9 && c < NF) ? w2g[m*NF + c] : 0.f;
    afrag[jj] = f2bf(wv);
  }

  if (lid < 144) s_w1[lid/NF][lid%NF] = w1g[lid];
  if (lid >= 192 && lid < 192+NF) {
    int c = lid - 192;
    float sc = gammag[c] * rsqrtf(mvg[c] + EPSV);
    s_bnA[c] = sc;
    s_bnB[c] = betag[c] - mmg[c]*sc;
    s_b1[c] = b1g[c];
  }

  for (int q = lid; q < GR*GR; q += 256) {
    int r = q / GR, c = q - r*GR;
    int gh = ty0 - 2 + r, gw = tx0 - 2 + c;
    float v = 0.f;
    if ((unsigned)gh < HH && (unsigned)gw < WW) v = gb[gh*WW + gw];
    s_grid[r][c] = v;
  }
  __syncthreads();

  // ---- phase A: conv1+relu+BN (fp32, quad-split channels) -> s_y1b bf16 ----
  {
    const int g = lid >> 2, k = lid & 3, c0 = k*4;
    float rw1[9][4], ra[4], rb[4], rbias[4];
    #pragma unroll
    for (int t = 0; t < 9; ++t)
      #pragma unroll
      for (int jj = 0; jj < 4; ++jj) rw1[t][jj] = s_w1[t][c0+jj];
    #pragma unroll
    for (int jj = 0; jj < 4; ++jj) { ra[jj]=s_bnA[c0+jj]; rb[jj]=s_bnB[c0+jj]; rbias[jj]=s_b1[c0+jj]; }

    for (int p = g; p < YRYR; p += 64) {
      int r = p / YR, c = p - r*YR;
      int yh = ty0 - 1 + r, yw = tx0 - 1 + c;
      float vmask = ((unsigned)yh < HH && (unsigned)yw < WW) ? 1.f : 0.f;
      float gg[9];
      #pragma unroll
      for (int dy = 0; dy < 3; ++dy)
        #pragma unroll
        for (int dx = 0; dx < 3; ++dx) gg[dy*3+dx] = s_grid[r+dy][c+dx];
      short4 hv;
      short* hp = (short*)&hv;
      #pragma unroll
      for (int jj = 0; jj < 4; ++jj) {
        float a = rbias[jj];
        #pragma unroll
        for (int t = 0; t < 9; ++t) a = fmaf(gg[t], rw1[t][jj], a);
        a = fmaxf(a, 0.f);
        hp[jj] = f2bf(vmask * fmaf(a, ra[jj], rb[jj]));  // OOB y1 -> 0
      }
      *(short4*)&s_y1b[p][c0] = hv;
    }
  }
  __syncthreads();

  // ---- phase P: proj[t][p] = sum_c w2[t][c]*y1[p][c] via one MFMA / 16 px ----
  {
    const int wid = lid >> 6;
    for (int grp = wid; grp < NGRP; grp += 4) {
      int p = grp*16 + (l & 15);
      bf16x8 bfrag = {0,0,0,0,0,0,0,0};     // B[k=ch][n=px]: k=(l>>4)*8+jj
      if (l < 32) bfrag = *(const bf16x8*)&s_y1b[p][(l >> 4)*8];
      f32x4 d = {0.f,0.f,0.f,0.f};
      d = __builtin_amdgcn_mfma_f32_16x16x32_bf16(afrag, bfrag, d, 0, 0, 0);
      #pragma unroll
      for (int r4 = 0; r4 < 4; ++r4) {
        int t = (l >> 4)*4 + r4;            // C: col=lane&15, row=(lane>>4)*4+reg
        if (t < 9) s_proj[p][t] = d[r4];
      }
    }
  }
  __syncthreads();

  // ---- phase B: out = b2 + sum_t proj[t] at shifted pixel ----
  {
    const int ty = lid >> 4, tx = lid & 15;
    float acc = b2g[0];
    #pragma unroll
    for (int kh = 0; kh < 3; ++kh)
      #pragma unroll
      for (int kw = 0; kw < 3; ++kw)
        acc += s_proj[(ty+kh)*YR + (tx+kw)][kh*3+kw];
    y[(size_t)b*HWSZ + (size_t)(ty0+ty)*WW + (tx0+tx)] = acc;
  }
}

extern "C" void kernel_launch(void* const* d_in, const int* in_sizes, int n_in,
                              void* d_out, int out_size, void* d_ws, size_t ws_size,
                              hipStream_t stream) {
  const float* x     = (const float*)d_in[0];
  const float* w1    = (const float*)d_in[1];
  const float* b1    = (const float*)d_in[2];
  const float* gamma = (const float*)d_in[3];
  const float* beta  = (const float*)d_in[4];
  const float* mmean = (const float*)d_in[5];
  const float* mvar  = (const float*)d_in[6];
  const float* w2    = (const float*)d_in[7];
  const float* b2    = (const float*)d_in[8];
  const int*   idx   = (const int*)d_in[9];
  float* out = (float*)d_out;

  float*    grid   = (float*)d_ws;                       // 33.5 MB
  float*    yout   = grid + (size_t)NB*HWSZ;             // 33.5 MB
  unsigned* g_cnt  = (unsigned*)(yout + (size_t)NB*HWSZ);// 64 B
  unsigned* g_bkt  = g_cnt + 16;                         // 16*8192*4 = 512 KB

  hipMemsetAsync(g_cnt, 0, NREG*sizeof(unsigned), stream);

  bin_k<<<dim3((NLD+255)/256), dim3(256), 0, stream>>>(idx, g_cnt, g_bkt);

  scatter_k<<<dim3(NB*NREG), dim3(256), 0, stream>>>(x, g_cnt, g_bkt, grid);

  conv_k<<<dim3(32 * (HH/TILE) * (WW/TILE)), dim3(256), 0, stream>>>(
      grid, w1, b1, gamma, beta, mmean, mvar, w2, b2, yout);

  int gblocks = 32 * ((NLD + 255) / 256);
  gather_k<<<dim3(gblocks), dim3(256), 0, stream>>>(x, idx, yout, out);
}

// Round 7
// 148.859 us; speedup vs baseline: 2.1979x; 1.2388x over previous
//
#include <hip/hip_runtime.h>
#include <hip/hip_bf16.h>

#define HH 512
#define WW 512
#define HWSZ (HH*WW)
#define NB 32
#define NLD 100000
#define NF 16
#define EPSV 1e-3f
#define TILE 16
#define GR (TILE+4)    // grid halo tile 20x20
#define YR (TILE+2)    // y1/proj tile 18x18
#define YRYR (YR*YR)   // 324
#define NGRP 21        // ceil(324/16) pixel-groups for MFMA
#define PSLOTS (NGRP*16)
#define PSTRB 20       // proj row stride in shorts (40B: 8B-aligned writes, bank-spread reads)

#define RGB 14              // log2 cells per scatter region
#define RCELLS (1<<RGB)     // 16384 cells = 64KB LDS
#define NREG (HWSZ/RCELLS)  // 16 regions per batch
#define CAP 8192            // region bucket capacity (λ=6250, σ=77)
#define NTILE 1024          // 32x32 tiles of 16x16
#define CAPT 256            // tile bucket capacity (λ=97.7, σ=9.9)

typedef __attribute__((ext_vector_type(8))) short bf16x8;
typedef __attribute__((ext_vector_type(4))) float f32x4;

static __device__ __forceinline__ unsigned short f2bfu(float f) {
  __hip_bfloat16 h = __float2bfloat16(f);
  return __builtin_bit_cast(unsigned short, h);
}

static __device__ __forceinline__ unsigned pkbf(float a, float b) {
  // pack two bf16 into one dword (low=a, high=b)
  return (unsigned)f2bfu(a) | ((unsigned)f2bfu(b) << 16);
}

// ---- prep: build the w2 MFMA A-fragment once (A[m=tap][k=ch], lane l holds
// m=l&15, k=(l>>4)*8+jj) so conv blocks load it as one dwordx4. ----
__global__ void prep_k(const float* __restrict__ w2g, uint4* __restrict__ w2A) {
  int l = threadIdx.x;  // 64
  bf16x8 a2;
  #pragma unroll
  for (int jj = 0; jj < 8; ++jj) {
    int m = l & 15, c = (l >> 4)*8 + jj;
    float v = (m < 9 && c < NF) ? w2g[m*NF + c] : 0.f;
    a2[jj] = (short)f2bfu(v);
  }
  w2A[l] = __builtin_bit_cast(uint4, a2);
}

// ---- bin: one pass over the (batch-independent) indices fills BOTH the
// 16 region buckets (for LDS-scatter) and the 1024 tile buckets (for the
// fused gather epilogue in conv_k). 64 blocks, 2-pass LDS histogram. ----
__global__ __launch_bounds__(256) void bin_k(const int* __restrict__ idx,
    unsigned* __restrict__ g_cnt, unsigned* __restrict__ g_bkt,
    unsigned* __restrict__ g_tcnt, unsigned* __restrict__ g_tbkt) {
  __shared__ unsigned hr[NREG], br[NREG], ht[NTILE], bt[NTILE];
  const int lid = threadIdx.x;
  if (lid < NREG) hr[lid] = 0;
  for (int q = lid; q < NTILE; q += 256) ht[q] = 0;
  __syncthreads();
  for (int i = blockIdx.x*256 + lid; i < NLD; i += 64*256) {
    int cell = idx[i];
    atomicAdd(&hr[cell >> RGB], 1u);
    int h = cell >> 9, w = cell & 511;
    atomicAdd(&ht[(h >> 4)*32 + (w >> 4)], 1u);
  }
  __syncthreads();
  if (lid < NREG) { br[lid] = atomicAdd(&g_cnt[lid], hr[lid]); hr[lid] = 0; }
  for (int q = lid; q < NTILE; q += 256) {
    bt[q] = ht[q] ? atomicAdd(&g_tcnt[q], ht[q]) : 0u;
    ht[q] = 0;
  }
  __syncthreads();
  for (int i = blockIdx.x*256 + lid; i < NLD; i += 64*256) {
    int cell = idx[i];
    int r = cell >> RGB;
    unsigned pr = br[r] + atomicAdd(&hr[r], 1u);
    if (pr < CAP) g_bkt[(size_t)r*CAP + pr] = ((unsigned)i << RGB) | (unsigned)(cell & (RCELLS-1));
    int h = cell >> 9, w = cell & 511;
    int t = (h >> 4)*32 + (w >> 4);
    unsigned pt = bt[t] + atomicAdd(&ht[t], 1u);
    if (pt < CAPT) g_tbkt[(size_t)t*CAPT + pt] =
        ((unsigned)i << 8) | ((unsigned)(h & 15) << 4) | (unsigned)(w & 15);
  }
}

// ---- scatter via LDS-privatized regions (proven R5): zero global atomics,
// absorbs grid zeroing. Block (b=j&31 -> XCD b%8, r=j>>5). ----
__global__ __launch_bounds__(256) void scatter_k(const float* __restrict__ x,
    const unsigned* __restrict__ g_cnt, const unsigned* __restrict__ g_bucket,
    float* __restrict__ grid) {
  __shared__ float s_acc[RCELLS];
  const int lid = threadIdx.x;
  const int j = blockIdx.x;
  const int b = j & 31;
  const int r = j >> 5;

  float4 z = make_float4(0.f, 0.f, 0.f, 0.f);
  for (int q = lid; q < RCELLS/4; q += 256) ((float4*)s_acc)[q] = z;
  __syncthreads();

  const unsigned n = min(g_cnt[r], (unsigned)CAP);
  const float* xb = x + (size_t)b*NLD;
  const unsigned* bk = g_bucket + (size_t)r*CAP;
  #pragma unroll 4
  for (unsigned k = lid; k < n; k += 256) {
    unsigned e = bk[k];
    atomicAdd(&s_acc[e & (RCELLS-1)], xb[e >> RGB]);   // ds_add_f32
  }
  __syncthreads();

  float* gout = grid + (size_t)b*HWSZ + ((size_t)r << RGB);
  for (int q = lid; q < RCELLS/4; q += 256)
    ((float4*)gout)[q] = ((const float4*)s_acc)[q];
}

__global__ __launch_bounds__(256) void conv_k(const float* __restrict__ grid,
    const float* __restrict__ w1g, const float* __restrict__ b1g,
    const float* __restrict__ gammag, const float* __restrict__ betag,
    const float* __restrict__ mmg, const float* __restrict__ mvg,
    const uint4* __restrict__ w2Ag, const float* __restrict__ b2g,
    const float* __restrict__ x,
    const unsigned* __restrict__ g_tcnt, const unsigned* __restrict__ g_tbkt,
    float* __restrict__ out)
{
  __shared__ float s_grid[GR*GR];                       // reused as y-tile in epilogue
  __shared__ __align__(16) short s_y1b[PSLOTS][NF];     // y1 post-BN, bf16
  __shared__ __align__(8) unsigned short s_projb[PSLOTS*PSTRB];  // proj bf16
  __shared__ float s_w1[9][NF];
  __shared__ float s_b1[NF], s_bnA[NF], s_bnB[NF];

  const int lid = threadIdx.x;
  const int j = blockIdx.x;
  const int b = j & 31;                    // XCD-affine batch
  const int tile = j >> 5;
  const int ty0 = (tile >> 5) * TILE, tx0 = (tile & 31) * TILE;
  const float* gb = grid + (size_t)b*HWSZ;

  const int l = lid & 63;
  const bf16x8 w2frag = __builtin_bit_cast(bf16x8, w2Ag[l]);

  if (lid < 144) s_w1[lid/NF][lid%NF] = w1g[lid];
  if (lid >= 192 && lid < 192+NF) {
    int c = lid - 192;
    float sc = gammag[c] * rsqrtf(mvg[c] + EPSV);
    s_bnA[c] = sc;
    s_bnB[c] = betag[c] - mmg[c]*sc;
    s_b1[c] = b1g[c];
  }

  // stage grid halo tile (zero = SAME padding for conv1)
  for (int q = lid; q < GR*GR; q += 256) {
    int r = q / GR, c = q - r*GR;
    int gh = ty0 - 2 + r, gw = tx0 - 2 + c;
    float v = 0.f;
    if ((unsigned)gh < HH && (unsigned)gw < WW) v = gb[gh*WW + gw];
    s_grid[q] = v;
  }
  __syncthreads();

  // ---- phase A: conv1+relu+BN (fp32, quad-split channels) -> s_y1b bf16 ----
  {
    const int g = lid >> 2, k = lid & 3, c0 = k*4;
    float rw1[9][4], ra[4], rb[4], rbias[4];
    #pragma unroll
    for (int t = 0; t < 9; ++t)
      #pragma unroll
      for (int jj = 0; jj < 4; ++jj) rw1[t][jj] = s_w1[t][c0+jj];
    #pragma unroll
    for (int jj = 0; jj < 4; ++jj) { ra[jj]=s_bnA[c0+jj]; rb[jj]=s_bnB[c0+jj]; rbias[jj]=s_b1[c0+jj]; }

    for (int p = g; p < YRYR; p += 64) {
      int r = p / YR, c = p - r*YR;
      int yh = ty0 - 1 + r, yw = tx0 - 1 + c;
      bool valid = ((unsigned)yh < HH) & ((unsigned)yw < WW);
      const float* gp = &s_grid[r*GR + c];
      float gg[9];
      #pragma unroll
      for (int dy = 0; dy < 3; ++dy)
        #pragma unroll
        for (int dx = 0; dx < 3; ++dx) gg[dy*3+dx] = gp[dy*GR + dx];
      float o[4];
      #pragma unroll
      for (int jj = 0; jj < 4; ++jj) {
        float a = rbias[jj];
        #pragma unroll
        for (int t = 0; t < 9; ++t) a = fmaf(gg[t], rw1[t][jj], a);
        a = fmaxf(a, 0.f);
        o[jj] = fmaf(a, ra[jj], rb[jj]);
      }
      unsigned u0 = valid ? pkbf(o[0], o[1]) : 0u;   // OOB y1 -> 0 (conv2 pads OUTPUT)
      unsigned u1 = valid ? pkbf(o[2], o[3]) : 0u;
      *(uint2*)&s_y1b[p][c0] = make_uint2(u0, u1);
    }
  }
  __syncthreads();

  // ---- phase P: proj[t][p] = sum_c w2[t][c]*y1[p][c] via one MFMA / 16 px ----
  {
    const int wid = lid >> 6;
    const int n_px = l & 15, kg = l >> 4;
    for (int grp = wid; grp < NGRP; grp += 4) {
      int p = grp*16 + n_px;
      bf16x8 bfrag = {0,0,0,0,0,0,0,0};     // B[k=ch][n=px]: k=(l>>4)*8+jj
      if (l < 32) bfrag = *(const bf16x8*)&s_y1b[p][kg*8];
      f32x4 d = {0.f,0.f,0.f,0.f};
      d = __builtin_amdgcn_mfma_f32_16x16x32_bf16(w2frag, bfrag, d, 0, 0, 0);
      // C: col=lane&15 (px), row=(lane>>4)*4+reg (tap); taps 9..15 are junk, never read
      unsigned v0 = pkbf(d[0], d[1]), v1 = pkbf(d[2], d[3]);
      *(uint2*)&s_projb[p*PSTRB + kg*4] = make_uint2(v0, v1);
    }
  }
  __syncthreads();

  // ---- phase B: out-tile = b2 + sum_t proj[t] at shifted pixel -> LDS ----
  {
    const int ty = lid >> 4, tx = lid & 15;
    float acc = b2g[0];
    #pragma unroll
    for (int kh = 0; kh < 3; ++kh)
      #pragma unroll
      for (int kw = 0; kw < 3; ++kw) {
        unsigned u = s_projb[((ty+kh)*YR + tx+kw)*PSTRB + kh*3+kw];
        acc += __uint_as_float(u << 16);
      }
    s_grid[lid] = acc;    // s_grid reused as the 16x16 y-tile
  }
  __syncthreads();

  // ---- fused gather epilogue: out[b,i] = x[b,i] + y_tile for this tile's entries ----
  {
    const unsigned nT = min(g_tcnt[tile], (unsigned)CAPT);
    const unsigned* tb = g_tbkt + (size_t)tile*CAPT;
    for (unsigned k2 = lid; k2 < nT; k2 += 256) {
      unsigned e = tb[k2];
      unsigned i = e >> 8;
      unsigned py = (e >> 4) & 15, px = e & 15;
      out[(size_t)b*NLD + i] = x[(size_t)b*NLD + i] + s_grid[py*16 + px];
    }
  }
}

extern "C" void kernel_launch(void* const* d_in, const int* in_sizes, int n_in,
                              void* d_out, int out_size, void* d_ws, size_t ws_size,
                              hipStream_t stream) {
  const float* x     = (const float*)d_in[0];
  const float* w1    = (const float*)d_in[1];
  const float* b1    = (const float*)d_in[2];
  const float* gamma = (const float*)d_in[3];
  const float* beta  = (const float*)d_in[4];
  const float* mmean = (const float*)d_in[5];
  const float* mvar  = (const float*)d_in[6];
  const float* w2    = (const float*)d_in[7];
  const float* b2    = (const float*)d_in[8];
  const int*   idx   = (const int*)d_in[9];
  float* out = (float*)d_out;

  float*    grid   = (float*)d_ws;                        // 33.55 MB
  unsigned* g_cnt  = (unsigned*)(grid + (size_t)NB*HWSZ); // 16
  unsigned* g_tcnt = g_cnt + NREG;                        // 1024
  unsigned* g_bkt  = g_tcnt + NTILE;                      // 512 KB
  unsigned* g_tbkt = g_bkt + (size_t)NREG*CAP;            // 1 MB
  uint4*    w2A    = (uint4*)(g_tbkt + (size_t)NTILE*CAPT);

  (void)hipMemsetAsync(g_cnt, 0, (NREG + NTILE)*sizeof(unsigned), stream);

  prep_k<<<dim3(1), dim3(64), 0, stream>>>(w2, w2A);

  bin_k<<<dim3(64), dim3(256), 0, stream>>>(idx, g_cnt, g_bkt, g_tcnt, g_tbkt);

  scatter_k<<<dim3(NB*NREG), dim3(256), 0, stream>>>(x, g_cnt, g_bkt, grid);

  conv_k<<<dim3(32 * (HH/TILE) * (WW/TILE)), dim3(256), 0, stream>>>(
      grid, w1, b1, gamma, beta, mmean, mvar, w2A, b2, x, g_tcnt, g_tbkt, out);
}